// Round 13
// baseline (2174.174 us; speedup 1.0000x reference)
//
#include <hip/hip_runtime.h>

// SparseCoding fused persistent kernel, fp32 VALU (R13).
// Arithmetic chains bit-identical to R1/R9 (absmax must stay 4.882812e-4).
//
// R10/R11/R12 all hit the same cliff: 32 state-slots/thread (a1+a2 = 64 regs)
// + accumulators ~= 96 live floats vs an 84-VGPR cap -> allocator bistable,
// spills to scratch (R12: 2.3 GB writes, L2 thrashed, W panels re-fetched
// from HBM by every block). R13 removes the cliff structurally:
//  - 512 threads/block -> 16 slots/thread -> a1+a2 = 32 regs, live ~80.
//  - __launch_bounds__(512,2): 128-VGPR cap, 16 waves/CU, LDS 40KB x2 = 80KB.
//  - register blocking up: phase 1 = 2 rows x 2 cols (16 FMA/ds_read_b128),
//    phase 2 = 4 rows x 4 cols (16 FMA/read). R9 was 4 FMA/read both phases.
//  - W4 pack [j/4][i][j%4] (phase 1: 2 adjacent dwordx4/iter, lane-dense);
//    Wt4 pack [i/4][j][i%4] (phase 2: 4 adjacent dwordx4/iter, lane-dense).
//  - x/d LDS traffic vectorized (b128 x-update, b64 d-write); broadcasts on
//    the read side (whole wave reads same row-slice -> conflict-free).
//  - step-0 phase 1 skipped: x0=0 -> acc == +0.0 exactly -> d0 = 0.0f - inp.

#define BSZ   32768
#define DIN   128
#define DOUT  512
#define RTILE 16
#define NSTEP 10
#define NT    512
#define NBLOCKS (BSZ / RTILE)   // 2048

typedef __attribute__((ext_vector_type(2))) float f32x2;

// pack both layouts (one-time, 256 KB each into ws)
__global__ void sc_pack(const float* __restrict__ W, float* __restrict__ W4,
                        float* __restrict__ Wt4) {
    const int tid = blockIdx.x * blockDim.x + threadIdx.x;  // 0..65535
    const int j = tid >> 7;      // 0..511 (coalesced read of W row-major)
    const int i = tid & 127;     // 0..127
    const float v = W[j * DIN + i];
    W4 [(j >> 2) * 512  + i * 4 + (j & 3)] = v;   // [j/4][i][j%4]
    Wt4[(i >> 2) * 2048 + j * 4 + (i & 3)] = v;   // [i/4][j][i%4]
}

__global__ __launch_bounds__(NT, 2)
void sc_fused(const float* __restrict__ inp, const float4* __restrict__ W4,
              const float4* __restrict__ Wt4, float* __restrict__ out)
{
    __shared__ float x_lds[RTILE][DOUT];    // 32 KB
    __shared__ float d_lds[RTILE][DIN];     //  8 KB  (40 KB total, 2 blk/CU)

    const int t = threadIdx.x;
    const int row0 = blockIdx.x * RTILE;

    // phase-1 mapping: 2 rows x 2 i-cols per thread
    const int rg = (t >> 6) * 2;     // {0,2,...,14}
    const int ic = (t & 63) * 2;     // {0,2,...,126}
    // phase-2 / update mapping: 4 rows x 4 j-cols per thread
    const int rg2 = (t >> 7) * 4;    // {0,4,8,12}
    const int jc  = (t & 127) * 4;   // {0,4,...,508}

    // per-thread RMSProp state: 16 slots
    float a1[4][4], a2[4][4];
#pragma unroll
    for (int r = 0; r < 4; ++r)
#pragma unroll
        for (int c = 0; c < 4; ++c) { a1[r][c] = 0.f; a2[r][c] = 0.f; }

    // inp values needed in phase 1 (registers, 8B loads)
    f32x2 inr[2];
#pragma unroll
    for (int rr = 0; rr < 2; ++rr)
        inr[rr] = *(const f32x2*)&inp[(row0 + rg + rr) * DIN + ic];

    // zero-init x (update at step 0 reads x=0; fully rewritten each step)
    {
        float4* xf4 = (float4*)&x_lds[0][0];
#pragma unroll
        for (int k = 0; k < 4; ++k) {
            float4 z; z.x = z.y = z.z = z.w = 0.f;
            xf4[t + k * NT] = z;   // 2048 float4s total
        }
    }

    // thread-fixed base pointers (float4-granular packed panels)
    const float4* __restrict__ w4p  = W4 + ic;    // + jb*128 (and +1)
    const float4* __restrict__ wt4p = Wt4 + jc;   // + ib*512 (+0..3)

    for (int step = 0; step < NSTEP; ++step) {
        // ---- phase 1: d = x @ W - inp ----
        if (step == 0) {
            // x0 = 0: fmaf chain is exactly +0.0 -> d = 0.0f - inp (bit-exact)
#pragma unroll
            for (int rr = 0; rr < 2; ++rr) {
                f32x2 dv; dv.x = 0.0f - inr[rr].x; dv.y = 0.0f - inr[rr].y;
                *(f32x2*)&d_lds[rg + rr][ic] = dv;
            }
        } else {
            float acc[2][2];
            acc[0][0] = acc[0][1] = acc[1][0] = acc[1][1] = 0.f;

#pragma unroll 2
            for (int jb = 0; jb < DOUT / 4; ++jb) {
                const float4 wa = w4p[jb * 128];       // W[4jb..4jb+3][ic]
                const float4 wb = w4p[jb * 128 + 1];   // W[4jb..4jb+3][ic+1]
                const float4 x0 = *(const float4*)&x_lds[rg + 0][jb * 4];  // broadcast
                const float4 x1 = *(const float4*)&x_lds[rg + 1][jb * 4];  // broadcast
                acc[0][0] = fmaf(x0.x, wa.x, acc[0][0]);
                acc[0][0] = fmaf(x0.y, wa.y, acc[0][0]);
                acc[0][0] = fmaf(x0.z, wa.z, acc[0][0]);
                acc[0][0] = fmaf(x0.w, wa.w, acc[0][0]);
                acc[0][1] = fmaf(x0.x, wb.x, acc[0][1]);
                acc[0][1] = fmaf(x0.y, wb.y, acc[0][1]);
                acc[0][1] = fmaf(x0.z, wb.z, acc[0][1]);
                acc[0][1] = fmaf(x0.w, wb.w, acc[0][1]);
                acc[1][0] = fmaf(x1.x, wa.x, acc[1][0]);
                acc[1][0] = fmaf(x1.y, wa.y, acc[1][0]);
                acc[1][0] = fmaf(x1.z, wa.z, acc[1][0]);
                acc[1][0] = fmaf(x1.w, wa.w, acc[1][0]);
                acc[1][1] = fmaf(x1.x, wb.x, acc[1][1]);
                acc[1][1] = fmaf(x1.y, wb.y, acc[1][1]);
                acc[1][1] = fmaf(x1.z, wb.z, acc[1][1]);
                acc[1][1] = fmaf(x1.w, wb.w, acc[1][1]);
            }
#pragma unroll
            for (int rr = 0; rr < 2; ++rr) {
                f32x2 dv;
                dv.x = acc[rr][0] - inr[rr].x;
                dv.y = acc[rr][1] - inr[rr].y;
                *(f32x2*)&d_lds[rg + rr][ic] = dv;
            }
        }
        __syncthreads();

        // ---- phase 2: gacc = d @ W^T (4 rows x 4 cols per thread) ----
        {
            float acc2[4][4];
#pragma unroll
            for (int r = 0; r < 4; ++r)
#pragma unroll
                for (int c = 0; c < 4; ++c) acc2[r][c] = 0.f;

#pragma unroll 2
            for (int ib = 0; ib < DIN / 4; ++ib) {
                const float4 q0 = wt4p[ib * 512 + 0];  // W[jc+0][4ib..4ib+3]
                const float4 q1 = wt4p[ib * 512 + 1];
                const float4 q2 = wt4p[ib * 512 + 2];
                const float4 q3 = wt4p[ib * 512 + 3];
#pragma unroll
                for (int rr = 0; rr < 4; ++rr) {
                    const float4 dv = *(const float4*)&d_lds[rg2 + rr][ib * 4];  // broadcast
                    acc2[rr][0] = fmaf(dv.x, q0.x, acc2[rr][0]);
                    acc2[rr][0] = fmaf(dv.y, q0.y, acc2[rr][0]);
                    acc2[rr][0] = fmaf(dv.z, q0.z, acc2[rr][0]);
                    acc2[rr][0] = fmaf(dv.w, q0.w, acc2[rr][0]);
                    acc2[rr][1] = fmaf(dv.x, q1.x, acc2[rr][1]);
                    acc2[rr][1] = fmaf(dv.y, q1.y, acc2[rr][1]);
                    acc2[rr][1] = fmaf(dv.z, q1.z, acc2[rr][1]);
                    acc2[rr][1] = fmaf(dv.w, q1.w, acc2[rr][1]);
                    acc2[rr][2] = fmaf(dv.x, q2.x, acc2[rr][2]);
                    acc2[rr][2] = fmaf(dv.y, q2.y, acc2[rr][2]);
                    acc2[rr][2] = fmaf(dv.z, q2.z, acc2[rr][2]);
                    acc2[rr][2] = fmaf(dv.w, q2.w, acc2[rr][2]);
                    acc2[rr][3] = fmaf(dv.x, q3.x, acc2[rr][3]);
                    acc2[rr][3] = fmaf(dv.y, q3.y, acc2[rr][3]);
                    acc2[rr][3] = fmaf(dv.z, q3.z, acc2[rr][3]);
                    acc2[rr][3] = fmaf(dv.w, q3.w, acc2[rr][3]);
                }
            }

            // RMSProp + momentum update (chains identical to R1), x via b128
#pragma unroll
            for (int rr = 0; rr < 4; ++rr) {
                float4 xv = *(const float4*)&x_lds[rg2 + rr][jc];
                float xn[4];
#pragma unroll
                for (int c = 0; c < 4; ++c) {
                    const float xs  = (c == 0) ? xv.x : (c == 1) ? xv.y
                                    : (c == 2) ? xv.z : xv.w;
                    const float g   = 2.f * acc2[rr][c] + 0.1f * xs * rsqrtf(xs * xs + 1e-6f);
                    const float na1 = 0.9f * a1[rr][c] + 0.1f * g * g;
                    a1[rr][c] = na1;
                    const float upd = 0.001f * g * rsqrtf(na1 + 1e-8f);
                    const float na2 = 0.9f * a2[rr][c] - upd;
                    a2[rr][c] = na2;
                    xn[c] = xs + 0.9f * na2 - upd;
                }
                float4 xo; xo.x = xn[0]; xo.y = xn[1]; xo.z = xn[2]; xo.w = xn[3];
                *(float4*)&x_lds[rg2 + rr][jc] = xo;
            }
            __syncthreads();
        }
    }

    // write final x (coalesced float4)
    {
        const float4* xf4 = (const float4*)&x_lds[0][0];
        float4* of4 = (float4*)(out + row0 * DOUT);
#pragma unroll
        for (int k = 0; k < 4; ++k)
            of4[t + k * NT] = xf4[t + k * NT];
    }
}

extern "C" void kernel_launch(void* const* d_in, const int* in_sizes, int n_in,
                              void* d_out, int out_size, void* d_ws, size_t ws_size,
                              hipStream_t stream) {
    const float* inputs = (const float*)d_in[0];
    const float* W      = (const float*)d_in[1];
    float* out          = (float*)d_out;
    float* W4           = (float*)d_ws;               // 256 KB
    float* Wt4          = (float*)d_ws + 65536;       // 256 KB

    sc_pack<<<dim3(256), dim3(256), 0, stream>>>(W, W4, Wt4);
    sc_fused<<<dim3(NBLOCKS), dim3(NT), 0, stream>>>(inputs, (const float4*)W4,
                                                     (const float4*)Wt4, out);
}

// Round 14
// 1787.393 us; speedup vs baseline: 1.2164x; 1.2164x over previous
//
#include <hip/hip_runtime.h>

// SparseCoding fused persistent kernel, fp32 VALU (R14).
// Arithmetic chains bit-identical to R1/R9 (absmax must stay 4.882812e-4).
//
// Round ledger driving this shape:
//  - W L1/L2 traffic = B / rows_per_thread per phase. R9 (8 rows p1 / 16 rows
//    p2) -> ~16 GB total; R13 (2/4) -> ~56 GB and VALUBusy fell to 47%.
//    => keep R9's thread mappings exactly.
//  - hipcc VGPR cap ~= 256/arg2 (R10:64, R11:40, R9/R12:84, R13:128).
//    R9 ran AT 84 with ~96 co-live floats -> bistable; R12's variant spilled.
//    => (256,2): cap 128. Residency stays 3 blocks/CU because LDS (48 KB) is
//    the binding limit -> same 12 waves/CU as R9, zero spill risk.
//  - W4 pack [j/4][i][j%4]: phase 1 reads ONE dwordx4 per 4-j (was 4 scalar
//    loads + 64-bit addr math). Wt4 pack [i/4][j][i%4]: phase 2 reads TWO
//    dwordx4 per 4-i. Both value-identical repackings (verified R10).
//  - Step 0 peeled (no in-loop branches, R12's suspected spill trigger):
//    x0=0 -> phase-1 chain is exactly +0.0 -> d0 = 0.0f - inp; peeled update
//    uses 0.0f constants in the SAME expression tree (runtime-identical).

#define BSZ   32768
#define DIN   128
#define DOUT  512
#define RTILE 16
#define NSTEP 10
#define NT    256
#define NBLOCKS (BSZ / RTILE)   // 2048

// pack both layouts (one-time, 256 KB each into ws)
__global__ void sc_pack(const float* __restrict__ W, float* __restrict__ W4,
                        float* __restrict__ Wt4) {
    const int tid = blockIdx.x * blockDim.x + threadIdx.x;  // 0..65535
    const int j = tid >> 7;      // 0..511 (coalesced read of W row-major)
    const int i = tid & 127;     // 0..127
    const float v = W[j * DIN + i];
    W4 [(j >> 2) * 512  + i * 4 + (j & 3)] = v;   // [j/4][i][j%4]
    Wt4[(i >> 2) * 2048 + j * 4 + (i & 3)] = v;   // [i/4][j][i%4]
}

__global__ __launch_bounds__(NT, 2)
void sc_fused(const float* __restrict__ inp, const float4* __restrict__ W4,
              const float4* __restrict__ Wt4, float* __restrict__ out)
{
    __shared__ float x_lds[RTILE][DOUT];    // 32 KB
    __shared__ float d_lds[RTILE][DIN];     //  8 KB
    __shared__ float inp_lds[RTILE][DIN];   //  8 KB  (48 KB -> 3 blocks/CU)

    const int t = threadIdx.x;
    const int row0 = blockIdx.x * RTILE;

    const int i_p1 = t & 127;        // phase-1 column (0..127)
    const int rg   = (t >> 7) * 8;   // phase-1 row group (0 or 8)
    const int j0   = 2 * t;          // phase-2/update column pair (0..510)

    // Per-thread RMSProp state (phase-2 mapping: 16 rows x 2 cols)
    float a1[RTILE][2];
    float a2[RTILE][2];

    // load inputs tile (coalesced)
    for (int k = t; k < RTILE * DIN; k += NT)
        (&inp_lds[0][0])[k] = inp[row0 * DIN + k];
    __syncthreads();

    // thread-fixed base pointers into packed panels (float4-granular)
    const float4* __restrict__ w4p  = W4 + i_p1;    // + jb*128
    const float4* __restrict__ wt4p = Wt4 + j0;     // + ib*512 (+1)

    // ================= peeled step 0 =================
    // x0 = 0: R1's phase-1 fmaf chain is exactly +0.0 -> d0 = 0.0f - inp.
#pragma unroll
    for (int rr = 0; rr < 8; ++rr)
        d_lds[rg + rr][i_p1] = 0.0f - inp_lds[rg + rr][i_p1];
    __syncthreads();

    {
        float acc2[RTILE][2];
#pragma unroll
        for (int r = 0; r < RTILE; ++r) acc2[r][0] = acc2[r][1] = 0.f;

#pragma unroll 2
        for (int ib = 0; ib < DIN / 4; ++ib) {
            const float4 qa = wt4p[ib * 512];       // W[j0][4ib..4ib+3]
            const float4 qb = wt4p[ib * 512 + 1];   // W[j0+1][4ib..4ib+3]
#pragma unroll
            for (int r = 0; r < RTILE; ++r) {
                const float4 dv = *(const float4*)&d_lds[r][ib * 4];  // broadcast
                acc2[r][0] = fmaf(dv.x, qa.x, acc2[r][0]);
                acc2[r][0] = fmaf(dv.y, qa.y, acc2[r][0]);
                acc2[r][0] = fmaf(dv.z, qa.z, acc2[r][0]);
                acc2[r][0] = fmaf(dv.w, qa.w, acc2[r][0]);
                acc2[r][1] = fmaf(dv.x, qb.x, acc2[r][1]);
                acc2[r][1] = fmaf(dv.y, qb.y, acc2[r][1]);
                acc2[r][1] = fmaf(dv.z, qb.z, acc2[r][1]);
                acc2[r][1] = fmaf(dv.w, qb.w, acc2[r][1]);
            }
        }

        // step-0 update: same expression tree with xv = a1 = a2 = 0.0f
#pragma unroll
        for (int r = 0; r < RTILE; ++r) {
#pragma unroll
            for (int c = 0; c < 2; ++c) {
                const float xv  = 0.0f;
                const float g   = 2.f * acc2[r][c] + 0.1f * xv * rsqrtf(xv * xv + 1e-6f);
                const float na1 = 0.9f * 0.0f + 0.1f * g * g;
                a1[r][c] = na1;
                const float upd = 0.001f * g * rsqrtf(na1 + 1e-8f);
                const float na2 = 0.9f * 0.0f - upd;
                a2[r][c] = na2;
                x_lds[r][j0 + c] = xv + 0.9f * na2 - upd;
            }
        }
    }
    __syncthreads();

    // ================= steps 1..9 =================
    for (int step = 1; step < NSTEP; ++step) {
        // ---- phase 1: d = x @ W - inp (8 rows x 1 col per thread) ----
        {
            float acc[8];
#pragma unroll
            for (int rr = 0; rr < 8; ++rr) acc[rr] = 0.f;

#pragma unroll 4
            for (int jb = 0; jb < DOUT / 4; ++jb) {
                const float4 wv = w4p[jb * 128];   // W[4jb..4jb+3][i_p1]
#pragma unroll
                for (int rr = 0; rr < 8; ++rr) {
                    const float4 xv = *(const float4*)&x_lds[rg + rr][jb * 4];  // broadcast
                    acc[rr] = fmaf(xv.x, wv.x, acc[rr]);
                    acc[rr] = fmaf(xv.y, wv.y, acc[rr]);
                    acc[rr] = fmaf(xv.z, wv.z, acc[rr]);
                    acc[rr] = fmaf(xv.w, wv.w, acc[rr]);
                }
            }
#pragma unroll
            for (int rr = 0; rr < 8; ++rr)
                d_lds[rg + rr][i_p1] = acc[rr] - inp_lds[rg + rr][i_p1];
        }
        __syncthreads();

        // ---- phase 2: gacc = d @ W^T (16 rows x 2 cols per thread) ----
        {
            float acc2[RTILE][2];
#pragma unroll
            for (int r = 0; r < RTILE; ++r) acc2[r][0] = acc2[r][1] = 0.f;

#pragma unroll 2
            for (int ib = 0; ib < DIN / 4; ++ib) {
                const float4 qa = wt4p[ib * 512];       // W[j0][4ib..4ib+3]
                const float4 qb = wt4p[ib * 512 + 1];   // W[j0+1][4ib..4ib+3]
#pragma unroll
                for (int r = 0; r < RTILE; ++r) {
                    const float4 dv = *(const float4*)&d_lds[r][ib * 4];  // broadcast
                    acc2[r][0] = fmaf(dv.x, qa.x, acc2[r][0]);
                    acc2[r][0] = fmaf(dv.y, qa.y, acc2[r][0]);
                    acc2[r][0] = fmaf(dv.z, qa.z, acc2[r][0]);
                    acc2[r][0] = fmaf(dv.w, qa.w, acc2[r][0]);
                    acc2[r][1] = fmaf(dv.x, qb.x, acc2[r][1]);
                    acc2[r][1] = fmaf(dv.y, qb.y, acc2[r][1]);
                    acc2[r][1] = fmaf(dv.z, qb.z, acc2[r][1]);
                    acc2[r][1] = fmaf(dv.w, qb.w, acc2[r][1]);
                }
            }

            // RMSProp + momentum update (chains identical to R1)
#pragma unroll
            for (int r = 0; r < RTILE; ++r) {
#pragma unroll
                for (int c = 0; c < 2; ++c) {
                    const float xv  = x_lds[r][j0 + c];
                    const float g   = 2.f * acc2[r][c] + 0.1f * xv * rsqrtf(xv * xv + 1e-6f);
                    const float na1 = 0.9f * a1[r][c] + 0.1f * g * g;
                    a1[r][c] = na1;
                    const float upd = 0.001f * g * rsqrtf(na1 + 1e-8f);
                    const float na2 = 0.9f * a2[r][c] - upd;
                    a2[r][c] = na2;
                    x_lds[r][j0 + c] = xv + 0.9f * na2 - upd;
                }
            }
        }
        __syncthreads();
    }

    // write final x (coalesced)
    for (int k = t; k < RTILE * DOUT; k += NT)
        out[row0 * DOUT + k] = (&x_lds[0][0])[k];
}

extern "C" void kernel_launch(void* const* d_in, const int* in_sizes, int n_in,
                              void* d_out, int out_size, void* d_ws, size_t ws_size,
                              hipStream_t stream) {
    const float* inputs = (const float*)d_in[0];
    const float* W      = (const float*)d_in[1];
    float* out          = (float*)d_out;
    float* W4           = (float*)d_ws;               // 256 KB
    float* Wt4          = (float*)d_ws + 65536;       // 256 KB

    sc_pack<<<dim3(256), dim3(256), 0, stream>>>(W, W4, Wt4);
    sc_fused<<<dim3(NBLOCKS), dim3(NT), 0, stream>>>(inputs, (const float4*)W4,
                                                     (const float4*)Wt4, out);
}